// Round 6
// baseline (203.595 us; speedup 1.0000x reference)
//
#include <hip/hip_runtime.h>

#define DIM 256
#define T_LEN 4096
#define K_CODES 1024
#define N_TOK 65536
#define NELEM 16777216

// ws layout (32-bit units):
//   [0,1024)      cnh2[k]  packed (bf16_hi | bf16_lo<<16) of 2+0.5|e|^2
//   [1024,2048)   loss partials (1024 f32, one per wave)
//   [4096,135168) cbb2: code book bf16, chunk-tiled (512 KB):
//                 cbb2[kc][oct][r][8]: byte = kc*16384 + oct*512 + r*16 + i*2
//                 holds cb[kc*32+r][oct*8 + i]  (oct = c>>3)

typedef __attribute__((ext_vector_type(8))) short bf16x8;
typedef __attribute__((ext_vector_type(16))) float f32x16;

__device__ __forceinline__ unsigned short f2bf(float f) {     // RNE f32->bf16
    unsigned u = __builtin_bit_cast(unsigned, f);
    return (unsigned short)((u + 0x7FFFu + ((u >> 16) & 1u)) >> 16);
}
__device__ __forceinline__ float bf2f(unsigned short h) {
    return __builtin_bit_cast(float, (unsigned)h << 16);
}
__device__ __forceinline__ unsigned f2u(float f) { return __builtin_bit_cast(unsigned, f); }
__device__ __forceinline__ float u2f(unsigned u) { return __builtin_bit_cast(float, u); }
__device__ __forceinline__ unsigned umin2(unsigned a, unsigned b) { return a < b ? a : b; }

union FragU { bf16x8 v; unsigned short u[8]; unsigned w[4]; };

// cvt two f32 -> packed bf16 pair, NEGATED (folds -x for the cn-fold trick), RNE.
__device__ __forceinline__ unsigned cvtpk_neg(float a, float b) {
    unsigned r;
    asm("v_cvt_pk_bf16_f32 %0, -%1, -%2" : "=v"(r) : "v"(a), "v"(b));
    return r;
}

// ---------------- prep: cb -> chunk-tiled bf16 + cnh2 split pair ----------------
__global__ __launch_bounds__(256) void prep(const float* __restrict__ cb,
                                            unsigned short* __restrict__ cbb2,
                                            unsigned* __restrict__ cnh2) {
    const int k = blockIdx.x * 4 + (threadIdx.x >> 6);
    const int lane = threadIdx.x & 63;
    float4 v = *reinterpret_cast<const float4*>(cb + (size_t)k * DIM + lane * 4);
    float s = v.x * v.x + v.y * v.y + v.z * v.z + v.w * v.w;
    #pragma unroll
    for (int off = 32; off; off >>= 1) s += __shfl_down(s, off);
    if (lane == 0) {
        float cn = 2.0f + 0.5f * s;
        unsigned short chi = f2bf(cn);
        unsigned short clo = f2bf(cn - bf2f(chi));
        cnh2[k] = (unsigned)chi | ((unsigned)clo << 16);
    }
    ushort4 o;
    o.x = f2bf(v.x); o.y = f2bf(v.y); o.z = f2bf(v.z); o.w = f2bf(v.w);
    const int c = lane * 4;
    const size_t dst = (size_t)(k >> 5) * 16384 + (size_t)(c >> 3) * 512
                     + (size_t)(k & 31) * 16 + (c & 7) * 2;
    *reinterpret_cast<ushort4*>((char*)cbb2 + dst) = o;
}

// ---------------- fused argmin + scatter + loss ----------------
// 512 blocks x 2 INDEPENDENT waves, 64 tokens each. No __syncthreads anywhere.
// Codebook swept directly from L2 (chunk-tiled, every frag load = coalesced 1KB).
__global__ __launch_bounds__(128, 2) void vq_fused(const float* __restrict__ x,
                                                   const unsigned short* __restrict__ cbb2,
                                                   const unsigned* __restrict__ cnh2,
                                                   const float* __restrict__ cbf,
                                                   float* __restrict__ out,
                                                   float* __restrict__ part) {
    __shared__ __align__(16) char ldsraw[2][17408];   // per-wave: bf16 x-tile / f32 out-tile
    __shared__ int kkl[2][64];
    const int tid = threadIdx.x;
    const int w = tid >> 6, lane = tid & 63, hi = lane >> 5, ln31 = lane & 31;
    const int tw = blockIdx.x * 128 + w * 64;
    const int b = tw >> 12, t0 = tw & (T_LEN - 1);
    char* lds = ldsraw[w];

    // ---- x ingest: 2 c-halves through the 16 KB bf16 tile; frags -> registers ----
    const int tq = lane & 15, cq = lane >> 4;
    const float* xb = x + (size_t)b * DIM * T_LEN + t0 + 4 * tq;
    FragU xf0[16], xf1[16];                 // NEGATED bf16 x frags (g=0 / g=1)
    float x2s = 0.0f;

    #pragma unroll
    for (int h = 0; h < 2; ++h) {
        #pragma unroll
        for (int ii = 0; ii < 8; ++ii) {
            const int cl = ii * 16 + cq * 4;                    // c within half
            const float* p = xb + (size_t)(h * 128 + cl) * T_LEN;
            const float4 P0 = *reinterpret_cast<const float4*>(p);
            const float4 P1 = *reinterpret_cast<const float4*>(p + T_LEN);
            const float4 P2 = *reinterpret_cast<const float4*>(p + 2 * T_LEN);
            const float4 P3 = *reinterpret_cast<const float4*>(p + 3 * T_LEN);
            x2s = fmaf(P0.x, P0.x, fmaf(P0.y, P0.y, fmaf(P0.z, P0.z, fmaf(P0.w, P0.w, x2s))));
            x2s = fmaf(P1.x, P1.x, fmaf(P1.y, P1.y, fmaf(P1.z, P1.z, fmaf(P1.w, P1.w, x2s))));
            x2s = fmaf(P2.x, P2.x, fmaf(P2.y, P2.y, fmaf(P2.z, P2.z, fmaf(P2.w, P2.w, x2s))));
            x2s = fmaf(P3.x, P3.x, fmaf(P3.y, P3.y, fmaf(P3.z, P3.z, fmaf(P3.w, P3.w, x2s))));
            const unsigned l0 = cvtpk_neg(P0.x, P0.y), h0 = cvtpk_neg(P0.z, P0.w);
            const unsigned l1 = cvtpk_neg(P1.x, P1.y), h1 = cvtpk_neg(P1.z, P1.w);
            const unsigned l2 = cvtpk_neg(P2.x, P2.y), h2 = cvtpk_neg(P2.z, P2.w);
            const unsigned l3 = cvtpk_neg(P3.x, P3.y), h3 = cvtpk_neg(P3.z, P3.w);
            const unsigned q0a = __builtin_amdgcn_perm(l1, l0, 0x05040100u);
            const unsigned q0b = __builtin_amdgcn_perm(l3, l2, 0x05040100u);
            const unsigned q1a = __builtin_amdgcn_perm(l1, l0, 0x07060302u);
            const unsigned q1b = __builtin_amdgcn_perm(l3, l2, 0x07060302u);
            const unsigned q2a = __builtin_amdgcn_perm(h1, h0, 0x05040100u);
            const unsigned q2b = __builtin_amdgcn_perm(h3, h2, 0x05040100u);
            const unsigned q3a = __builtin_amdgcn_perm(h1, h0, 0x07060302u);
            const unsigned q3b = __builtin_amdgcn_perm(h3, h2, 0x07060302u);
            const int tb4 = 4 * tq, cb2 = cl * 2;
            uint2 u;
            u.x = q0a; u.y = q0b;
            *reinterpret_cast<uint2*>(lds + ((((tb4 + 0) << 8) + cb2) ^ (((tb4 + 0) & 15) << 4))) = u;
            u.x = q1a; u.y = q1b;
            *reinterpret_cast<uint2*>(lds + ((((tb4 + 1) << 8) + cb2) ^ (((tb4 + 1) & 15) << 4))) = u;
            u.x = q2a; u.y = q2b;
            *reinterpret_cast<uint2*>(lds + ((((tb4 + 2) << 8) + cb2) ^ (((tb4 + 2) & 15) << 4))) = u;
            u.x = q3a; u.y = q3b;
            *reinterpret_cast<uint2*>(lds + ((((tb4 + 3) << 8) + cb2) ^ (((tb4 + 3) & 15) << 4))) = u;
        }
        #pragma unroll
        for (int g = 0; g < 2; ++g) {
            const int tp = g * 32 + ln31;
            #pragma unroll
            for (int cfl = 0; cfl < 8; ++cfl) {
                int ad = (tp << 8) + cfl * 32 + hi * 16;
                ad ^= (tp & 15) << 4;
                if (g == 0) xf0[h * 8 + cfl].v = *reinterpret_cast<const bf16x8*>(lds + ad);
                else        xf1[h * 8 + cfl].v = *reinterpret_cast<const bf16x8*>(lds + ad);
            }
        }
    }

    // ---- codebook sweep from L2: 32 chunks of 32 codes, barrier-free ----
    FragU onef;                                   // B-const: k=0,1 -> 1.0
    #pragma unroll
    for (int i = 0; i < 8; ++i) onef.u[i] = (hi == 0 && i < 2) ? 0x3F80 : 0;

    unsigned best0 = 0xFFFFFFFFu, best1 = 0xFFFFFFFFu;

    for (int kc = 0; kc < 32; ++kc) {
        const char* cbase = (const char*)cbb2 + kc * 16384 + lane * 16;
        const unsigned d = cnh2[kc * 32 + ln31];
        FragU cfr;
        cfr.u[0] = hi ? (unsigned short)0 : (unsigned short)(d & 0xFFFFu);
        cfr.u[1] = hi ? (unsigned short)0 : (unsigned short)(d >> 16);
        #pragma unroll
        for (int i = 2; i < 8; ++i) cfr.u[i] = 0;

        f32x16 acc0, acc1;
        #pragma unroll
        for (int i = 0; i < 16; ++i) { acc0[i] = 0.0f; acc1[i] = 0.0f; }
        acc0 = __builtin_amdgcn_mfma_f32_32x32x16_bf16(cfr.v, onef.v, acc0, 0, 0, 0);
        acc1 = __builtin_amdgcn_mfma_f32_32x32x16_bf16(cfr.v, onef.v, acc1, 0, 0, 0);

        bf16x8 af[8];
        #pragma unroll
        for (int cf = 0; cf < 8; ++cf)
            af[cf] = *reinterpret_cast<const bf16x8*>(cbase + cf * 1024);
        #pragma unroll
        for (int cf = 0; cf < 8; ++cf) {
            acc0 = __builtin_amdgcn_mfma_f32_32x32x16_bf16(af[cf], xf0[cf].v, acc0, 0, 0, 0);
            acc1 = __builtin_amdgcn_mfma_f32_32x32x16_bf16(af[cf], xf1[cf].v, acc1, 0, 0, 0);
        }
        #pragma unroll
        for (int cf = 0; cf < 8; ++cf)
            af[cf] = *reinterpret_cast<const bf16x8*>(cbase + (cf + 8) * 1024);
        #pragma unroll
        for (int cf = 0; cf < 8; ++cf) {
            acc0 = __builtin_amdgcn_mfma_f32_32x32x16_bf16(af[cf], xf0[cf + 8].v, acc0, 0, 0, 0);
            acc1 = __builtin_amdgcn_mfma_f32_32x32x16_bf16(af[cf], xf1[cf + 8].v, acc1, 0, 0, 0);
        }

        const unsigned klane = kc * 32 + hi * 4;
        #pragma unroll
        for (int rg = 0; rg < 16; ++rg) {
            const unsigned crg = klane | (unsigned)((rg & 3) + 8 * (rg >> 2));
            best0 = umin2(best0, (f2u(acc0[rg]) & 0xFFFFFC00u) | crg);
            best1 = umin2(best1, (f2u(acc1[rg]) & 0xFFFFFC00u) | crg);
        }
    }

    // merge hi-halves (disjoint code subsets, same token columns)
    best0 = umin2(best0, __shfl_xor(best0, 32));
    best1 = umin2(best1, __shfl_xor(best1, 32));
    const unsigned mykey = hi ? best1 : best0;      // token = tw + lane
    kkl[w][lane] = (int)(mykey & 1023u);

    // loss partial: per-token 2*(s-2) + per-lane |x|^2 ingest partial
    float red = 2.0f * (u2f(mykey & 0xFFFFFC00u) - 2.0f) + x2s;
    #pragma unroll
    for (int off = 32; off; off >>= 1) red += __shfl_down(red, off);
    if (lane == 0) part[blockIdx.x * 2 + w] = red;

    // ---- fused scatter epilogue: gather cb rows -> LDS transpose -> coalesced out ----
    float* fs = (float*)lds;                        // [64 c][68 t] f32, 17408 B
    const int rq = lane >> 4, cc = lane & 15;
    #pragma unroll
    for (int q = 0; q < 4; ++q) {
        #pragma unroll 4
        for (int it = 0; it < 16; ++it) {
            const int row = kkl[w][it * 4 + rq];
            const float4 v = *reinterpret_cast<const float4*>(
                cbf + (size_t)row * DIM + q * 64 + cc * 4);
            fs[(cc * 4 + 0) * 68 + it * 4 + rq] = v.x;
            fs[(cc * 4 + 1) * 68 + it * 4 + rq] = v.y;
            fs[(cc * 4 + 2) * 68 + it * 4 + rq] = v.z;
            fs[(cc * 4 + 3) * 68 + it * 4 + rq] = v.w;
        }
        #pragma unroll 4
        for (int rr = 0; rr < 16; ++rr) {
            const int c_loc = rr * 4 + rq;
            const float4 ov = *reinterpret_cast<const float4*>(fs + c_loc * 68 + 4 * cc);
            *reinterpret_cast<float4*>(
                out + (((size_t)(b * 256 + q * 64 + c_loc)) << 12) + t0 + 4 * cc) = ov;
        }
    }
}

// ---------------- finalize loss ----------------
__global__ __launch_bounds__(256) void finalize(const float* __restrict__ part,
                                                float* __restrict__ loss_out) {
    double s = 0.0;
    for (int i = threadIdx.x; i < 1024; i += 256) s += (double)part[i];
    #pragma unroll
    for (int off = 32; off; off >>= 1) s += __shfl_down(s, off);
    __shared__ double wsum[4];
    const int lane = threadIdx.x & 63, wv = threadIdx.x >> 6;
    if (lane == 0) wsum[wv] = s;
    __syncthreads();
    if (threadIdx.x == 0)
        *loss_out = (float)(2.0 * (wsum[0] + wsum[1] + wsum[2] + wsum[3]) / (double)NELEM);
}

extern "C" void kernel_launch(void* const* d_in, const int* in_sizes, int n_in,
                              void* d_out, int out_size, void* d_ws, size_t ws_size,
                              hipStream_t stream) {
    const float* x  = (const float*)d_in[0];        // [16,256,4096]
    const float* cb = (const float*)d_in[1];        // [1024,256]
    float* out = (float*)d_out;                     // quant (16777216) + loss (1)
    unsigned* ws = (unsigned*)d_ws;
    unsigned* cnh2 = ws;                            // 1024 u32
    float* part = (float*)(ws + 1024);              // 1024 f32
    unsigned short* cbb2 = (unsigned short*)(ws + 4096);  // 512 KB tiled bf16 codebook

    prep<<<K_CODES / 4, 256, 0, stream>>>(cb, cbb2, cnh2);
    vq_fused<<<N_TOK / 128, 128, 0, stream>>>(x, cbb2, cnh2, cb, out, part);
    finalize<<<1, 256, 0, stream>>>(part, out + NELEM);
}

// Round 7
// 70.802 us; speedup vs baseline: 2.8756x; 2.8756x over previous
//
#include <hip/hip_runtime.h>

#define DIM 256
#define T_LEN 4096
#define K_CODES 1024
#define N_TOK 65536
#define NELEM 16777216

// ws layout (32-bit units):
//   [0,1024)      cnh2[k]  packed (bf16_hi | bf16_lo<<16) of 2+0.5|e|^2
//   [1024,1536)   loss partials (512 f32, one per argmin block)
//   [4096,69632)  keys[t]  packed (score_bits & ~1023) | code  (uint)
// d_out[0..131071] floats double as cb_bf16 scratch (512 KB): written by prep,
// read by argmin, dead before scatter overwrites d_out.

typedef __attribute__((ext_vector_type(8))) short bf16x8;
typedef __attribute__((ext_vector_type(16))) float f32x16;

__device__ __forceinline__ unsigned short f2bf(float f) {     // RNE f32->bf16
    unsigned u = __builtin_bit_cast(unsigned, f);
    return (unsigned short)((u + 0x7FFFu + ((u >> 16) & 1u)) >> 16);
}
__device__ __forceinline__ float bf2f(unsigned short h) {
    return __builtin_bit_cast(float, (unsigned)h << 16);
}
__device__ __forceinline__ unsigned f2u(float f) { return __builtin_bit_cast(unsigned, f); }
__device__ __forceinline__ float u2f(unsigned u) { return __builtin_bit_cast(float, u); }
__device__ __forceinline__ unsigned umin2(unsigned a, unsigned b) { return a < b ? a : b; }

union FragU { bf16x8 v; unsigned short u[8]; unsigned w[4]; };

#define GLLOAD(gsrc, lbase)                                                              \
    __builtin_amdgcn_global_load_lds(                                                    \
        (const __attribute__((address_space(1))) unsigned int*)(gsrc),                   \
        (__attribute__((address_space(3))) unsigned int*)(lbase), 16, 0, 0)

// cvt two f32 -> packed bf16 pair, NEGATED (folds -x for the cn-fold trick), RNE.
__device__ __forceinline__ unsigned cvtpk_neg(float a, float b) {
    unsigned r;
    asm("v_cvt_pk_bf16_f32 %0, -%1, -%2" : "=v"(r) : "v"(a), "v"(b));
    return r;
}

// ---------------- prep: cb->bf16 (row-major), cnh2 split pair ----------------
__global__ __launch_bounds__(256) void prep(const float* __restrict__ cb,
                                            unsigned short* __restrict__ cbb,
                                            unsigned* __restrict__ cnh2) {
    const int k = blockIdx.x * 4 + (threadIdx.x >> 6);
    const int lane = threadIdx.x & 63;
    float4 v = *reinterpret_cast<const float4*>(cb + (size_t)k * DIM + lane * 4);
    float s = v.x * v.x + v.y * v.y + v.z * v.z + v.w * v.w;
    #pragma unroll
    for (int off = 32; off; off >>= 1) s += __shfl_down(s, off);
    if (lane == 0) {
        float cn = 2.0f + 0.5f * s;
        unsigned short chi = f2bf(cn);
        unsigned short clo = f2bf(cn - bf2f(chi));
        cnh2[k] = (unsigned)chi | ((unsigned)clo << 16);
    }
    ushort4 o;
    o.x = f2bf(v.x); o.y = f2bf(v.y); o.z = f2bf(v.z); o.w = f2bf(v.w);
    *reinterpret_cast<ushort4*>(cbb + (size_t)k * DIM + lane * 4) = o;
}

// ---------------- argmin via MFMA + fused loss ----------------
// 512 blocks x 4 waves x 32 tokens/wave (128 tok/block) -> 2 blocks/CU,
// 2 waves/SIMD. LDS: 2x32KB chunk dbuf (also x-ingest scratch) + 4KB cnl.
// Inner loop VMEM-free (cn folded into MFMA); r5-proven staging/swizzles.
__global__ __launch_bounds__(256, 2) void argmin_mfma(const float* __restrict__ x,
                                                      const unsigned short* __restrict__ cbb,
                                                      const unsigned* __restrict__ cnh2,
                                                      unsigned* __restrict__ keys,
                                                      float* __restrict__ part) {
    __shared__ __align__(16) unsigned short cbuf[2][64 * 256];  // 2 x 32 KB
    __shared__ unsigned cnl[1024];                              // 4 KB
    __shared__ float wsum[4];
    const int tid = threadIdx.x;
    const int w = tid >> 6, lane = tid & 63, hi = lane >> 5, ln31 = lane & 31;
    const int tw0 = blockIdx.x * 128;                 // block token base
    const int b = tw0 >> 12, tb = tw0 & (T_LEN - 1);

    cnl[tid] = cnh2[tid];
    cnl[tid + 256] = cnh2[tid + 256];
    cnl[tid + 512] = cnh2[tid + 512];
    cnl[tid + 768] = cnh2[tid + 768];

    // ---- x ingest: [128 t][128 c] bf16 tile per half, half h -> cbuf[h] ----
    // thread -> (t-quad tqi = tid&31, c-quad cqi = tid>>5); 4 ii-steps/half.
    const int tqi = tid & 31, cqi = tid >> 5;
    const float* xb = x + (size_t)b * DIM * T_LEN + tb + 4 * tqi;
    const int wswz = (tqi & 7) << 4;
    FragU xf[16];                       // NEGATED bf16 x frags (this wave's 32 tokens)
    float x2s = 0.0f;

    #pragma unroll
    for (int h = 0; h < 2; ++h) {
        char* lds = (char*)&cbuf[h][0];
        #pragma unroll
        for (int ii = 0; ii < 4; ++ii) {
            const int cl = (ii * 8 + cqi) * 4;                  // c within half (0..124)
            const float* p = xb + (size_t)(h * 128 + cl) * T_LEN;
            const float4 P0 = *reinterpret_cast<const float4*>(p);
            const float4 P1 = *reinterpret_cast<const float4*>(p + T_LEN);
            const float4 P2 = *reinterpret_cast<const float4*>(p + 2 * T_LEN);
            const float4 P3 = *reinterpret_cast<const float4*>(p + 3 * T_LEN);
            x2s = fmaf(P0.x, P0.x, fmaf(P0.y, P0.y, fmaf(P0.z, P0.z, fmaf(P0.w, P0.w, x2s))));
            x2s = fmaf(P1.x, P1.x, fmaf(P1.y, P1.y, fmaf(P1.z, P1.z, fmaf(P1.w, P1.w, x2s))));
            x2s = fmaf(P2.x, P2.x, fmaf(P2.y, P2.y, fmaf(P2.z, P2.z, fmaf(P2.w, P2.w, x2s))));
            x2s = fmaf(P3.x, P3.x, fmaf(P3.y, P3.y, fmaf(P3.z, P3.z, fmaf(P3.w, P3.w, x2s))));
            const unsigned l0 = cvtpk_neg(P0.x, P0.y), h0 = cvtpk_neg(P0.z, P0.w);
            const unsigned l1 = cvtpk_neg(P1.x, P1.y), h1 = cvtpk_neg(P1.z, P1.w);
            const unsigned l2 = cvtpk_neg(P2.x, P2.y), h2 = cvtpk_neg(P2.z, P2.w);
            const unsigned l3 = cvtpk_neg(P3.x, P3.y), h3 = cvtpk_neg(P3.z, P3.w);
            // in-lane 4x4 transpose: token t gets (c0,c1) and (c2,c3) pairs
            const unsigned q0a = __builtin_amdgcn_perm(l1, l0, 0x05040100u);
            const unsigned q0b = __builtin_amdgcn_perm(h1, h0, 0x05040100u);
            const unsigned q1a = __builtin_amdgcn_perm(l1, l0, 0x07060302u);
            const unsigned q1b = __builtin_amdgcn_perm(h1, h0, 0x07060302u);
            const unsigned q2a = __builtin_amdgcn_perm(l3, l2, 0x05040100u);
            const unsigned q2b = __builtin_amdgcn_perm(h3, h2, 0x05040100u);
            const unsigned q3a = __builtin_amdgcn_perm(l3, l2, 0x07060302u);
            const unsigned q3b = __builtin_amdgcn_perm(h3, h2, 0x07060302u);
            const int t4 = 4 * tqi, cb2 = cl * 2;
            uint2 u;
            u.x = q0a; u.y = q0b;   // wait: q0b must be t0's (c2,c3)
            // NOTE: q0a = {bf(P0.x),bf(P1.x)} = t0 (c0,c1); q0b = {bf(P2.x),bf(P3.x)} = t0 (c2,c3)
            *reinterpret_cast<uint2*>(lds + ((((t4 + 0) << 8) + cb2) ^ wswz)) = u;
            u.x = q1a; u.y = q1b;
            *reinterpret_cast<uint2*>(lds + ((((t4 + 1) << 8) + cb2) ^ wswz)) = u;
            u.x = q2a; u.y = q2b;
            *reinterpret_cast<uint2*>(lds + ((((t4 + 2) << 8) + cb2) ^ wswz)) = u;
            u.x = q3a; u.y = q3b;
            *reinterpret_cast<uint2*>(lds + ((((t4 + 3) << 8) + cb2) ^ wswz)) = u;
        }
    }
    __syncthreads();
    {
        const int tp = w * 32 + ln31;                 // this wave's token row in tile
        const int rswz = ((tp >> 2) & 7) << 4;
        #pragma unroll
        for (int h = 0; h < 2; ++h) {
            const char* lds = (const char*)&cbuf[h][0];
            #pragma unroll
            for (int cf = 0; cf < 8; ++cf) {
                int ad = (tp << 8) + cf * 32 + hi * 16;
                xf[h * 8 + cf].v = *reinterpret_cast<const bf16x8*>(lds + (ad ^ rswz));
            }
        }
    }
    __syncthreads();

    // ---- codebook chunk staging (r5-proven): linear dest, pre-swizzled source ----
    auto stage = [&](int kc, int buf) {
        const char* gc = (const char*)cbb + kc * 32768;
        char* lb = (char*)&cbuf[buf][0];
        #pragma unroll
        for (int j = 0; j < 8; ++j) {
            int o = j * 4096 + w * 1024 + lane * 16;
            int so = o ^ (((o >> 9) & 31) << 4);
            GLLOAD(gc + so, lb + j * 4096 + w * 1024);
        }
    };
    stage(0, 0);

    FragU onef;                                   // B-const: k=0,1 -> 1.0
    #pragma unroll
    for (int i = 0; i < 8; ++i) onef.u[i] = (hi == 0 && i < 2) ? 0x3F80 : 0;

    unsigned best = 0xFFFFFFFFu;

    for (int kc = 0; kc < 16; ++kc) {
        const int cur = kc & 1;
        if (kc < 15) {
            stage(kc + 1, cur ^ 1);
            asm volatile("s_waitcnt vmcnt(8)" ::: "memory");
        } else {
            asm volatile("s_waitcnt vmcnt(0)" ::: "memory");
        }
        __syncthreads();

        const char* cbp = (const char*)&cbuf[cur][0];
        #pragma unroll
        for (int ct = 0; ct < 2; ++ct) {
            const int r = ct * 32 + ln31;
            bf16x8 af[16];
            #pragma unroll
            for (int cf = 0; cf < 16; ++cf) {
                int cbyte = cf * 32 + hi * 16;
                af[cf] = *(const bf16x8*)(cbp + r * 512 + (cbyte ^ ((r & 31) << 4)));
            }
            const unsigned d = cnl[kc * 64 + ct * 32 + ln31];
            FragU cfr;
            cfr.u[0] = hi ? (unsigned short)0 : (unsigned short)(d & 0xFFFFu);
            cfr.u[1] = hi ? (unsigned short)0 : (unsigned short)(d >> 16);
            #pragma unroll
            for (int i = 2; i < 8; ++i) cfr.u[i] = 0;

            f32x16 acc;
            #pragma unroll
            for (int i = 0; i < 16; ++i) acc[i] = 0.0f;
            acc = __builtin_amdgcn_mfma_f32_32x32x16_bf16(cfr.v, onef.v, acc, 0, 0, 0);
            #pragma unroll
            for (int cf = 0; cf < 16; ++cf)
                acc = __builtin_amdgcn_mfma_f32_32x32x16_bf16(af[cf], xf[cf].v, acc, 0, 0, 0);

            const int kbl = kc * 64 + ct * 32 + hi * 4;
            #pragma unroll
            for (int rg = 0; rg < 16; ++rg) {
                const unsigned kk = (unsigned)(kbl + (rg & 3) + 8 * (rg >> 2));
                best = umin2(best, (f2u(acc[rg]) & 0xFFFFFC00u) | kk);
            }
        }
        __syncthreads();
    }

    // lanes l and l^32: same token, disjoint code subsets -> merge
    best = umin2(best, __shfl_xor(best, 32));
    if (hi == 0) keys[tw0 + w * 32 + ln31] = best;

    // loss partial: per-token 2*(s-2) (hi==0 lanes only) + per-lane |x|^2
    float red = (hi ? 0.0f : 2.0f * (u2f(best & 0xFFFFFC00u) - 2.0f)) + x2s;
    #pragma unroll
    for (int off = 32; off; off >>= 1) red += __shfl_down(red, off);
    if (lane == 0) wsum[w] = red;
    __syncthreads();
    if (tid == 0) part[blockIdx.x] = wsum[0] + wsum[1] + wsum[2] + wsum[3];
}

// ---------------- scatter: gather cb rows -> LDS transpose -> coalesced out ----------------
__global__ __launch_bounds__(256) void scatter(const float* __restrict__ cb,
                                               const unsigned* __restrict__ keys,
                                               float* __restrict__ out) {
    __shared__ float xs[DIM][36];
    __shared__ int kk[32];
    const int tid = threadIdx.x;
    const int n0 = blockIdx.x * 32;
    const int b = n0 >> 12, t0 = n0 & (T_LEN - 1);

    if (tid < 32) kk[tid] = (int)(keys[n0 + tid] & 1023u);
    __syncthreads();

    {   // phase 1: coalesced row gather (float4) -> LDS transpose
        const int w = tid >> 6, l = tid & 63, tt = l & 31, q0 = l >> 5;
        const float* row = cb + (size_t)kk[tt] * DIM;
        #pragma unroll
        for (int r = 0; r < 8; ++r) {
            const int q = r * 8 + w * 2 + q0;
            const float4 v = *reinterpret_cast<const float4*>(row + q * 4);
            xs[q * 4 + 0][tt] = v.x;
            xs[q * 4 + 1][tt] = v.y;
            xs[q * 4 + 2][tt] = v.z;
            xs[q * 4 + 3][tt] = v.w;
        }
    }
    __syncthreads();

    {   // phase 2: coalesced float2 writes over t
        const int c16 = tid >> 4, th = tid & 15;
        #pragma unroll
        for (int r = 0; r < 16; ++r) {
            const int c = r * 16 + c16;
            const float2 v = *reinterpret_cast<const float2*>(&xs[c][2 * th]);
            *reinterpret_cast<float2*>(&out[(((size_t)b * DIM + c) << 12) + t0 + 2 * th]) = v;
        }
    }
}

// ---------------- finalize loss ----------------
__global__ __launch_bounds__(256) void finalize(const float* __restrict__ part,
                                                float* __restrict__ loss_out) {
    double s = (double)part[threadIdx.x] + (double)part[threadIdx.x + 256];
    #pragma unroll
    for (int off = 32; off; off >>= 1) s += __shfl_down(s, off);
    __shared__ double wsum[4];
    const int lane = threadIdx.x & 63, wv = threadIdx.x >> 6;
    if (lane == 0) wsum[wv] = s;
    __syncthreads();
    if (threadIdx.x == 0)
        *loss_out = (float)(2.0 * (wsum[0] + wsum[1] + wsum[2] + wsum[3]) / (double)NELEM);
}

extern "C" void kernel_launch(void* const* d_in, const int* in_sizes, int n_in,
                              void* d_out, int out_size, void* d_ws, size_t ws_size,
                              hipStream_t stream) {
    const float* x  = (const float*)d_in[0];    // [16,256,4096]
    const float* cb = (const float*)d_in[1];    // [1024,256]
    float* out = (float*)d_out;                 // quant (16777216) + loss (1)
    unsigned* ws = (unsigned*)d_ws;
    unsigned* cnh2 = ws;                        // 1024 u32
    float* part = (float*)(ws + 1024);          // 512 f32
    unsigned* keys = ws + 4096;                 // 65536 u32
    unsigned short* cbb = (unsigned short*)out; // 512 KB scratch; dead before scatter

    prep<<<K_CODES / 4, 256, 0, stream>>>(cb, cbb, cnh2);
    argmin_mfma<<<N_TOK / 128, 256, 0, stream>>>(x, cbb, cnh2, keys, part);
    scatter<<<N_TOK / 32, 256, 0, stream>>>(cb, keys, out);
    finalize<<<1, 256, 0, stream>>>(part, out + NELEM);
}

// Round 8
// 70.569 us; speedup vs baseline: 2.8851x; 1.0033x over previous
//
#include <hip/hip_runtime.h>

#define DIM 256
#define T_LEN 4096
#define K_CODES 1024
#define N_TOK 65536
#define NELEM 16777216

// ws layout (32-bit units):
//   [0,1024)      cnh2[k]  packed (bf16_hi | bf16_lo<<16) of 2+0.5|e|^2
//   [1024,1536)   loss partials (512 f32, one per argmin block)
//   [4096,69632)  keys[t]  packed (score_bits & ~1023) | code  (uint)
// d_out[0..131071] floats double as cb_bf16 scratch (512 KB): written by prep,
// read by argmin, dead before scatter overwrites d_out.

typedef __attribute__((ext_vector_type(8))) short bf16x8;
typedef __attribute__((ext_vector_type(16))) float f32x16;

__device__ __forceinline__ unsigned short f2bf(float f) {     // RNE f32->bf16
    unsigned u = __builtin_bit_cast(unsigned, f);
    return (unsigned short)((u + 0x7FFFu + ((u >> 16) & 1u)) >> 16);
}
__device__ __forceinline__ float bf2f(unsigned short h) {
    return __builtin_bit_cast(float, (unsigned)h << 16);
}
__device__ __forceinline__ unsigned f2u(float f) { return __builtin_bit_cast(unsigned, f); }
__device__ __forceinline__ float u2f(unsigned u) { return __builtin_bit_cast(float, u); }
__device__ __forceinline__ unsigned umin2(unsigned a, unsigned b) { return a < b ? a : b; }

union FragU { bf16x8 v; unsigned short u[8]; unsigned w[4]; };

#define GLLOAD(gsrc, lbase)                                                              \
    __builtin_amdgcn_global_load_lds(                                                    \
        (const __attribute__((address_space(1))) unsigned int*)(gsrc),                   \
        (__attribute__((address_space(3))) unsigned int*)(lbase), 16, 0, 0)

// cvt two f32 -> packed bf16 pair, NEGATED (folds -x for the cn-fold trick), RNE.
__device__ __forceinline__ unsigned cvtpk_neg(float a, float b) {
    unsigned r;
    asm("v_cvt_pk_bf16_f32 %0, -%1, -%2" : "=v"(r) : "v"(a), "v"(b));
    return r;
}

// ---------------- prep: cb->bf16 (row-major), cnh2 split pair ----------------
__global__ __launch_bounds__(256) void prep(const float* __restrict__ cb,
                                            unsigned short* __restrict__ cbb,
                                            unsigned* __restrict__ cnh2) {
    const int k = blockIdx.x * 4 + (threadIdx.x >> 6);
    const int lane = threadIdx.x & 63;
    float4 v = *reinterpret_cast<const float4*>(cb + (size_t)k * DIM + lane * 4);
    float s = v.x * v.x + v.y * v.y + v.z * v.z + v.w * v.w;
    #pragma unroll
    for (int off = 32; off; off >>= 1) s += __shfl_down(s, off);
    if (lane == 0) {
        float cn = 2.0f + 0.5f * s;
        unsigned short chi = f2bf(cn);
        unsigned short clo = f2bf(cn - bf2f(chi));
        cnh2[k] = (unsigned)chi | ((unsigned)clo << 16);
    }
    ushort4 o;
    o.x = f2bf(v.x); o.y = f2bf(v.y); o.z = f2bf(v.z); o.w = f2bf(v.w);
    *reinterpret_cast<ushort4*>(cbb + (size_t)k * DIM + lane * 4) = o;
}

// ---------------- argmin via MFMA + fused loss ----------------
// 512 blocks x 4 waves x 32 tokens/wave (128 tok/block) -> 2 blocks/CU,
// 2 waves/SIMD. K-loop uses RAW s_barrier + counted vmcnt(8): the chunk-k+1
// prefetch stays in flight across the barriers (__syncthreads would emit
// s_waitcnt vmcnt(0) and serialize every chunk on its stage latency).
__global__ __launch_bounds__(256, 2) void argmin_mfma(const float* __restrict__ x,
                                                      const unsigned short* __restrict__ cbb,
                                                      const unsigned* __restrict__ cnh2,
                                                      unsigned* __restrict__ keys,
                                                      float* __restrict__ part) {
    __shared__ __align__(16) unsigned short cbuf[2][64 * 256];  // 2 x 32 KB
    __shared__ unsigned cnl[1024];                              // 4 KB
    __shared__ float wsum[4];
    const int tid = threadIdx.x;
    const int w = tid >> 6, lane = tid & 63, hi = lane >> 5, ln31 = lane & 31;
    const int tw0 = blockIdx.x * 128;                 // block token base
    const int b = tw0 >> 12, tb = tw0 & (T_LEN - 1);

    cnl[tid] = cnh2[tid];
    cnl[tid + 256] = cnh2[tid + 256];
    cnl[tid + 512] = cnh2[tid + 512];
    cnl[tid + 768] = cnh2[tid + 768];

    // ---- x ingest: [128 t][128 c] bf16 tile per half, half h -> cbuf[h] ----
    const int tqi = tid & 31, cqi = tid >> 5;
    const float* xb = x + (size_t)b * DIM * T_LEN + tb + 4 * tqi;
    const int wswz = (tqi & 7) << 4;
    FragU xf[16];                       // NEGATED bf16 x frags (this wave's 32 tokens)
    float x2s = 0.0f;

    #pragma unroll
    for (int h = 0; h < 2; ++h) {
        char* lds = (char*)&cbuf[h][0];
        #pragma unroll
        for (int ii = 0; ii < 4; ++ii) {
            const int cl = (ii * 8 + cqi) * 4;                  // c within half (0..124)
            const float* p = xb + (size_t)(h * 128 + cl) * T_LEN;
            const float4 P0 = *reinterpret_cast<const float4*>(p);
            const float4 P1 = *reinterpret_cast<const float4*>(p + T_LEN);
            const float4 P2 = *reinterpret_cast<const float4*>(p + 2 * T_LEN);
            const float4 P3 = *reinterpret_cast<const float4*>(p + 3 * T_LEN);
            x2s = fmaf(P0.x, P0.x, fmaf(P0.y, P0.y, fmaf(P0.z, P0.z, fmaf(P0.w, P0.w, x2s))));
            x2s = fmaf(P1.x, P1.x, fmaf(P1.y, P1.y, fmaf(P1.z, P1.z, fmaf(P1.w, P1.w, x2s))));
            x2s = fmaf(P2.x, P2.x, fmaf(P2.y, P2.y, fmaf(P2.z, P2.z, fmaf(P2.w, P2.w, x2s))));
            x2s = fmaf(P3.x, P3.x, fmaf(P3.y, P3.y, fmaf(P3.z, P3.z, fmaf(P3.w, P3.w, x2s))));
            const unsigned l0 = cvtpk_neg(P0.x, P0.y), h0 = cvtpk_neg(P0.z, P0.w);
            const unsigned l1 = cvtpk_neg(P1.x, P1.y), h1 = cvtpk_neg(P1.z, P1.w);
            const unsigned l2 = cvtpk_neg(P2.x, P2.y), h2 = cvtpk_neg(P2.z, P2.w);
            const unsigned l3 = cvtpk_neg(P3.x, P3.y), h3 = cvtpk_neg(P3.z, P3.w);
            // in-lane 4x4 transpose: token t gets (c0,c1) and (c2,c3) pairs
            const unsigned q0a = __builtin_amdgcn_perm(l1, l0, 0x05040100u);
            const unsigned q0b = __builtin_amdgcn_perm(h1, h0, 0x05040100u);
            const unsigned q1a = __builtin_amdgcn_perm(l1, l0, 0x07060302u);
            const unsigned q1b = __builtin_amdgcn_perm(h1, h0, 0x07060302u);
            const unsigned q2a = __builtin_amdgcn_perm(l3, l2, 0x05040100u);
            const unsigned q2b = __builtin_amdgcn_perm(h3, h2, 0x05040100u);
            const unsigned q3a = __builtin_amdgcn_perm(l3, l2, 0x07060302u);
            const unsigned q3b = __builtin_amdgcn_perm(h3, h2, 0x07060302u);
            const int t4 = 4 * tqi, cb2 = cl * 2;
            uint2 u;
            u.x = q0a; u.y = q0b;
            *reinterpret_cast<uint2*>(lds + ((((t4 + 0) << 8) + cb2) ^ wswz)) = u;
            u.x = q1a; u.y = q1b;
            *reinterpret_cast<uint2*>(lds + ((((t4 + 1) << 8) + cb2) ^ wswz)) = u;
            u.x = q2a; u.y = q2b;
            *reinterpret_cast<uint2*>(lds + ((((t4 + 2) << 8) + cb2) ^ wswz)) = u;
            u.x = q3a; u.y = q3b;
            *reinterpret_cast<uint2*>(lds + ((((t4 + 3) << 8) + cb2) ^ wswz)) = u;
        }
    }
    __syncthreads();
    {
        const int tp = w * 32 + ln31;                 // this wave's token row in tile
        const int rswz = ((tp >> 2) & 7) << 4;
        #pragma unroll
        for (int h = 0; h < 2; ++h) {
            const char* lds = (const char*)&cbuf[h][0];
            #pragma unroll
            for (int cf = 0; cf < 8; ++cf) {
                int ad = (tp << 8) + cf * 32 + hi * 16;
                xf[h * 8 + cf].v = *reinterpret_cast<const bf16x8*>(lds + (ad ^ rswz));
            }
        }
    }
    __syncthreads();

    // ---- codebook chunk staging: linear dest, pre-swizzled source ----
    auto stage = [&](int kc, int buf) {
        const char* gc = (const char*)cbb + kc * 32768;
        char* lb = (char*)&cbuf[buf][0];
        #pragma unroll
        for (int j = 0; j < 8; ++j) {
            int o = j * 4096 + w * 1024 + lane * 16;
            int so = o ^ (((o >> 9) & 31) << 4);
            GLLOAD(gc + so, lb + j * 4096 + w * 1024);
        }
    };
    stage(0, 0);

    FragU onef;                                   // B-const: k=0,1 -> 1.0
    #pragma unroll
    for (int i = 0; i < 8; ++i) onef.u[i] = (hi == 0 && i < 2) ? 0x3F80 : 0;

    unsigned best = 0xFFFFFFFFu;

    for (int kc = 0; kc < 16; ++kc) {
        const int cur = kc & 1;
        if (kc < 15) {
            stage(kc + 1, cur ^ 1);
            asm volatile("s_waitcnt vmcnt(8)" ::: "memory");   // chunk kc landed; 8 prefetch in flight
        } else {
            asm volatile("s_waitcnt vmcnt(0)" ::: "memory");
        }
        __builtin_amdgcn_s_barrier();              // RAW: does NOT drain the prefetch
        __builtin_amdgcn_sched_barrier(0);

        const char* cbp = (const char*)&cbuf[cur][0];
        #pragma unroll
        for (int ct = 0; ct < 2; ++ct) {
            const int r = ct * 32 + ln31;
            bf16x8 af[16];
            #pragma unroll
            for (int cf = 0; cf < 16; ++cf) {
                int cbyte = cf * 32 + hi * 16;
                af[cf] = *(const bf16x8*)(cbp + r * 512 + (cbyte ^ ((r & 31) << 4)));
            }
            const unsigned d = cnl[kc * 64 + ct * 32 + ln31];
            FragU cfr;
            cfr.u[0] = hi ? (unsigned short)0 : (unsigned short)(d & 0xFFFFu);
            cfr.u[1] = hi ? (unsigned short)0 : (unsigned short)(d >> 16);
            #pragma unroll
            for (int i = 2; i < 8; ++i) cfr.u[i] = 0;

            f32x16 acc;
            #pragma unroll
            for (int i = 0; i < 16; ++i) acc[i] = 0.0f;
            acc = __builtin_amdgcn_mfma_f32_32x32x16_bf16(cfr.v, onef.v, acc, 0, 0, 0);
            #pragma unroll
            for (int cf = 0; cf < 16; ++cf)
                acc = __builtin_amdgcn_mfma_f32_32x32x16_bf16(af[cf], xf[cf].v, acc, 0, 0, 0);

            const int kbl = kc * 64 + ct * 32 + hi * 4;
            #pragma unroll
            for (int rg = 0; rg < 16; ++rg) {
                const unsigned kk = (unsigned)(kbl + (rg & 3) + 8 * (rg >> 2));
                best = umin2(best, (f2u(acc[rg]) & 0xFFFFFC00u) | kk);
            }
        }
        __builtin_amdgcn_s_barrier();              // RAW: all reads of buf[cur] done (lgkm
        __builtin_amdgcn_sched_barrier(0);         // consumed by MFMAs) before next stage
    }

    // lanes l and l^32: same token, disjoint code subsets -> merge
    best = umin2(best, __shfl_xor(best, 32));
    if (hi == 0) keys[tw0 + w * 32 + ln31] = best;

    // loss partial: per-token 2*(s-2) (hi==0 lanes only) + per-lane |x|^2
    float red = (hi ? 0.0f : 2.0f * (u2f(best & 0xFFFFFC00u) - 2.0f)) + x2s;
    #pragma unroll
    for (int off = 32; off; off >>= 1) red += __shfl_down(red, off);
    if (lane == 0) wsum[w] = red;
    __syncthreads();
    if (tid == 0) part[blockIdx.x] = wsum[0] + wsum[1] + wsum[2] + wsum[3];
}

// ---------------- scatter: gather cb rows -> LDS transpose -> coalesced out ----------------
__global__ __launch_bounds__(256) void scatter(const float* __restrict__ cb,
                                               const unsigned* __restrict__ keys,
                                               float* __restrict__ out) {
    __shared__ float xs[DIM][36];
    __shared__ int kk[32];
    const int tid = threadIdx.x;
    const int n0 = blockIdx.x * 32;
    const int b = n0 >> 12, t0 = n0 & (T_LEN - 1);

    if (tid < 32) kk[tid] = (int)(keys[n0 + tid] & 1023u);
    __syncthreads();

    {   // phase 1: coalesced row gather (float4) -> LDS transpose
        const int w = tid >> 6, l = tid & 63, tt = l & 31, q0 = l >> 5;
        const float* row = cb + (size_t)kk[tt] * DIM;
        #pragma unroll
        for (int r = 0; r < 8; ++r) {
            const int q = r * 8 + w * 2 + q0;
            const float4 v = *reinterpret_cast<const float4*>(row + q * 4);
            xs[q * 4 + 0][tt] = v.x;
            xs[q * 4 + 1][tt] = v.y;
            xs[q * 4 + 2][tt] = v.z;
            xs[q * 4 + 3][tt] = v.w;
        }
    }
    __syncthreads();

    {   // phase 2: coalesced float2 writes over t
        const int c16 = tid >> 4, th = tid & 15;
        #pragma unroll
        for (int r = 0; r < 16; ++r) {
            const int c = r * 16 + c16;
            const float2 v = *reinterpret_cast<const float2*>(&xs[c][2 * th]);
            *reinterpret_cast<float2*>(&out[(((size_t)b * DIM + c) << 12) + t0 + 2 * th]) = v;
        }
    }
}

// ---------------- finalize loss ----------------
__global__ __launch_bounds__(256) void finalize(const float* __restrict__ part,
                                                float* __restrict__ loss_out) {
    double s = (double)part[threadIdx.x] + (double)part[threadIdx.x + 256];
    #pragma unroll
    for (int off = 32; off; off >>= 1) s += __shfl_down(s, off);
    __shared__ double wsum[4];
    const int lane = threadIdx.x & 63, wv = threadIdx.x >> 6;
    if (lane == 0) wsum[wv] = s;
    __syncthreads();
    if (threadIdx.x == 0)
        *loss_out = (float)(2.0 * (wsum[0] + wsum[1] + wsum[2] + wsum[3]) / (double)NELEM);
}

extern "C" void kernel_launch(void* const* d_in, const int* in_sizes, int n_in,
                              void* d_out, int out_size, void* d_ws, size_t ws_size,
                              hipStream_t stream) {
    const float* x  = (const float*)d_in[0];    // [16,256,4096]
    const float* cb = (const float*)d_in[1];    // [1024,256]
    float* out = (float*)d_out;                 // quant (16777216) + loss (1)
    unsigned* ws = (unsigned*)d_ws;
    unsigned* cnh2 = ws;                        // 1024 u32
    float* part = (float*)(ws + 1024);          // 512 f32
    unsigned* keys = ws + 4096;                 // 65536 u32
    unsigned short* cbb = (unsigned short*)out; // 512 KB scratch; dead before scatter

    prep<<<K_CODES / 4, 256, 0, stream>>>(cb, cbb, cnh2);
    argmin_mfma<<<N_TOK / 128, 256, 0, stream>>>(x, cbb, cnh2, keys, part);
    scatter<<<N_TOK / 32, 256, 0, stream>>>(cb, keys, out);
    finalize<<<1, 256, 0, stream>>>(part, out + NELEM);
}

// Round 9
// 67.327 us; speedup vs baseline: 3.0240x; 1.0481x over previous
//
#include <hip/hip_runtime.h>

#define DIM 256
#define T_LEN 4096
#define K_CODES 1024
#define N_TOK 65536
#define NELEM 16777216

// ws layout (32-bit units):
//   [0,1024)      cnh2[k]  packed (bf16_hi | bf16_lo<<16) of 2+0.5|e|^2
//   [1024,1536)   loss partials (512 f32, one per argmin block)
//   [4096,69632)  keys[t]  packed (score_bits & ~1023) | code  (uint)
// d_out[0..131071] floats double as cb_bf16 scratch (512 KB): written by prep,
// read by argmin, dead before scatter overwrites d_out.

typedef __attribute__((ext_vector_type(8))) short bf16x8;
typedef __attribute__((ext_vector_type(16))) float f32x16;

__device__ __forceinline__ unsigned short f2bf(float f) {     // RNE f32->bf16
    unsigned u = __builtin_bit_cast(unsigned, f);
    return (unsigned short)((u + 0x7FFFu + ((u >> 16) & 1u)) >> 16);
}
__device__ __forceinline__ float bf2f(unsigned short h) {
    return __builtin_bit_cast(float, (unsigned)h << 16);
}
__device__ __forceinline__ unsigned f2u(float f) { return __builtin_bit_cast(unsigned, f); }
__device__ __forceinline__ float u2f(unsigned u) { return __builtin_bit_cast(float, u); }
__device__ __forceinline__ unsigned umin2(unsigned a, unsigned b) { return a < b ? a : b; }

union FragU { bf16x8 v; unsigned short u[8]; unsigned w[4]; };

#define GLLOAD(gsrc, lbase)                                                              \
    __builtin_amdgcn_global_load_lds(                                                    \
        (const __attribute__((address_space(1))) unsigned int*)(gsrc),                   \
        (__attribute__((address_space(3))) unsigned int*)(lbase), 16, 0, 0)

// cvt two f32 -> packed bf16 pair, NEGATED (folds -x for the cn-fold trick), RNE.
__device__ __forceinline__ unsigned cvtpk_neg(float a, float b) {
    unsigned r;
    asm("v_cvt_pk_bf16_f32 %0, -%1, -%2" : "=v"(r) : "v"(a), "v"(b));
    return r;
}

// ---------------- prep: cb->bf16 (row-major), cnh2 split pair ----------------
__global__ __launch_bounds__(256) void prep(const float* __restrict__ cb,
                                            unsigned short* __restrict__ cbb,
                                            unsigned* __restrict__ cnh2) {
    const int k = blockIdx.x * 4 + (threadIdx.x >> 6);
    const int lane = threadIdx.x & 63;
    float4 v = *reinterpret_cast<const float4*>(cb + (size_t)k * DIM + lane * 4);
    float s = v.x * v.x + v.y * v.y + v.z * v.z + v.w * v.w;
    #pragma unroll
    for (int off = 32; off; off >>= 1) s += __shfl_down(s, off);
    if (lane == 0) {
        float cn = 2.0f + 0.5f * s;
        unsigned short chi = f2bf(cn);
        unsigned short clo = f2bf(cn - bf2f(chi));
        cnh2[k] = (unsigned)chi | ((unsigned)clo << 16);
    }
    ushort4 o;
    o.x = f2bf(v.x); o.y = f2bf(v.y); o.z = f2bf(v.z); o.w = f2bf(v.w);
    *reinterpret_cast<ushort4*>(cbb + (size_t)k * DIM + lane * 4) = o;
}

// ---------------- argmin via MFMA, K-split wave pairs ----------------
// 512 blocks x 4 waves. Wave pair (2i,2i+1) shares 64 tokens; wave 2i sweeps
// codes 0-511, wave 2i+1 codes 512-1023 (16 chunks of 32 codes each), merged
// via LDS at the end. Halves total LDS codebook traffic (each wave reads
// 256 KB not 512 KB) while keeping 8 waves/CU. Inner loop VMEM-free; raw
// s_barrier + counted vmcnt(8) keeps prefetch in flight.
__global__ __launch_bounds__(256, 2) void argmin_mfma(const float* __restrict__ x,
                                                      const unsigned short* __restrict__ cbb,
                                                      const unsigned* __restrict__ cnh2,
                                                      unsigned* __restrict__ keys,
                                                      float* __restrict__ part) {
    __shared__ __align__(16) unsigned short cbuf[2][16 * 1024];  // 2 x 32 KB
    __shared__ unsigned cnl[1024];                               // 4 KB
    __shared__ unsigned kbx[4][64];                              // 1 KB key exchange
    __shared__ float wsum[4];
    const int tid = threadIdx.x;
    const int w = tid >> 6, lane = tid & 63, hi = lane >> 5, ln31 = lane & 31;
    const int tg = w >> 1;                    // token group (0,1): 64 tokens each
    const int kh = w & 1;                     // codebook half (0,1)
    const int tw0 = blockIdx.x * 128;
    const int b = tw0 >> 12, tb = tw0 & (T_LEN - 1);

    cnl[tid] = cnh2[tid];
    cnl[tid + 256] = cnh2[tid + 256];
    cnl[tid + 512] = cnh2[tid + 512];
    cnl[tid + 768] = cnh2[tid + 768];

    // ---- x ingest: [128 t][128 c] bf16 tile per c-half, half h -> cbuf[h] ----
    const int tqi = tid & 31, cqi = tid >> 5;
    const float* xb = x + (size_t)b * DIM * T_LEN + tb + 4 * tqi;
    const int wswz = (tqi & 7) << 4;
    float x2s = 0.0f;

    #pragma unroll
    for (int h = 0; h < 2; ++h) {
        char* lds = (char*)&cbuf[h][0];
        #pragma unroll
        for (int ii = 0; ii < 4; ++ii) {
            const int cl = (ii * 8 + cqi) * 4;                  // c within half
            const float* p = xb + (size_t)(h * 128 + cl) * T_LEN;
            const float4 P0 = *reinterpret_cast<const float4*>(p);
            const float4 P1 = *reinterpret_cast<const float4*>(p + T_LEN);
            const float4 P2 = *reinterpret_cast<const float4*>(p + 2 * T_LEN);
            const float4 P3 = *reinterpret_cast<const float4*>(p + 3 * T_LEN);
            x2s = fmaf(P0.x, P0.x, fmaf(P0.y, P0.y, fmaf(P0.z, P0.z, fmaf(P0.w, P0.w, x2s))));
            x2s = fmaf(P1.x, P1.x, fmaf(P1.y, P1.y, fmaf(P1.z, P1.z, fmaf(P1.w, P1.w, x2s))));
            x2s = fmaf(P2.x, P2.x, fmaf(P2.y, P2.y, fmaf(P2.z, P2.z, fmaf(P2.w, P2.w, x2s))));
            x2s = fmaf(P3.x, P3.x, fmaf(P3.y, P3.y, fmaf(P3.z, P3.z, fmaf(P3.w, P3.w, x2s))));
            const unsigned l0 = cvtpk_neg(P0.x, P0.y), h0 = cvtpk_neg(P0.z, P0.w);
            const unsigned l1 = cvtpk_neg(P1.x, P1.y), h1 = cvtpk_neg(P1.z, P1.w);
            const unsigned l2 = cvtpk_neg(P2.x, P2.y), h2 = cvtpk_neg(P2.z, P2.w);
            const unsigned l3 = cvtpk_neg(P3.x, P3.y), h3 = cvtpk_neg(P3.z, P3.w);
            const unsigned q0a = __builtin_amdgcn_perm(l1, l0, 0x05040100u);
            const unsigned q0b = __builtin_amdgcn_perm(h1, h0, 0x05040100u);
            const unsigned q1a = __builtin_amdgcn_perm(l1, l0, 0x07060302u);
            const unsigned q1b = __builtin_amdgcn_perm(h1, h0, 0x07060302u);
            const unsigned q2a = __builtin_amdgcn_perm(l3, l2, 0x05040100u);
            const unsigned q2b = __builtin_amdgcn_perm(h3, h2, 0x05040100u);
            const unsigned q3a = __builtin_amdgcn_perm(l3, l2, 0x07060302u);
            const unsigned q3b = __builtin_amdgcn_perm(h3, h2, 0x07060302u);
            const int t4 = 4 * tqi, cb2 = cl * 2;
            uint2 u;
            u.x = q0a; u.y = q0b;
            *reinterpret_cast<uint2*>(lds + ((((t4 + 0) << 8) + cb2) ^ wswz)) = u;
            u.x = q1a; u.y = q1b;
            *reinterpret_cast<uint2*>(lds + ((((t4 + 1) << 8) + cb2) ^ wswz)) = u;
            u.x = q2a; u.y = q2b;
            *reinterpret_cast<uint2*>(lds + ((((t4 + 2) << 8) + cb2) ^ wswz)) = u;
            u.x = q3a; u.y = q3b;
            *reinterpret_cast<uint2*>(lds + ((((t4 + 3) << 8) + cb2) ^ wswz)) = u;
        }
    }
    __syncthreads();
    FragU xf[2][16];                    // NEGATED bf16 frags: this pair's 64 tokens
    {
        #pragma unroll
        for (int g = 0; g < 2; ++g) {
            const int tp = tg * 64 + g * 32 + ln31;
            const int rswz = ((tp >> 2) & 7) << 4;
            #pragma unroll
            for (int h = 0; h < 2; ++h) {
                const char* lds = (const char*)&cbuf[h][0];
                #pragma unroll
                for (int cf = 0; cf < 8; ++cf) {
                    int ad = (tp << 8) + cf * 32 + hi * 16;
                    xf[g][h * 8 + cf].v = *reinterpret_cast<const bf16x8*>(lds + (ad ^ rswz));
                }
            }
        }
    }
    __syncthreads();

    // ---- staging: both halves' chunk kc (2 x 16 KB) into buf ----
    auto stage = [&](int kc, int buf) {
        char* lb = (char*)&cbuf[buf][0];
        const char* g0 = (const char*)cbb + kc * 16384;            // codes kc*32..
        const char* g1 = (const char*)cbb + 262144 + kc * 16384;   // codes 512+kc*32..
        #pragma unroll
        for (int j = 0; j < 8; ++j) {
            const int jj = j & 3;
            const int o = jj * 4096 + w * 1024 + lane * 16;
            const int so = o ^ (((o >> 9) & 31) << 4);
            GLLOAD((j < 4 ? g0 : g1) + so, lb + (j >> 2) * 16384 + jj * 4096 + w * 1024);
        }
    };
    stage(0, 0);

    FragU onef;                                   // B-const: k=0,1 -> 1.0
    #pragma unroll
    for (int i = 0; i < 8; ++i) onef.u[i] = (hi == 0 && i < 2) ? 0x3F80 : 0;

    unsigned b0a = 0xFFFFFFFFu, b0b = 0xFFFFFFFFu;   // acc0 chains
    unsigned b1a = 0xFFFFFFFFu, b1b = 0xFFFFFFFFu;   // acc1 chains

    for (int kc = 0; kc < 16; ++kc) {
        const int cur = kc & 1;
        if (kc < 15) {
            stage(kc + 1, cur ^ 1);
            asm volatile("s_waitcnt vmcnt(8)" ::: "memory");   // chunk kc landed
        } else {
            asm volatile("s_waitcnt vmcnt(0)" ::: "memory");
        }
        __builtin_amdgcn_s_barrier();
        __builtin_amdgcn_sched_barrier(0);

        const char* cbp = (const char*)&cbuf[cur][0] + kh * 16384;
        const unsigned d = cnl[kh * 512 + kc * 32 + ln31];
        FragU cfr;
        cfr.u[0] = hi ? (unsigned short)0 : (unsigned short)(d & 0xFFFFu);
        cfr.u[1] = hi ? (unsigned short)0 : (unsigned short)(d >> 16);
        #pragma unroll
        for (int i = 2; i < 8; ++i) cfr.u[i] = 0;

        f32x16 acc0, acc1;
        #pragma unroll
        for (int i = 0; i < 16; ++i) { acc0[i] = 0.0f; acc1[i] = 0.0f; }
        acc0 = __builtin_amdgcn_mfma_f32_32x32x16_bf16(cfr.v, onef.v, acc0, 0, 0, 0);
        acc1 = __builtin_amdgcn_mfma_f32_32x32x16_bf16(cfr.v, onef.v, acc1, 0, 0, 0);

        const int rbase = ln31 * 512;
        #pragma unroll
        for (int hf = 0; hf < 2; ++hf) {            // two 8-frag halves: af reuse
            bf16x8 af[8];
            #pragma unroll
            for (int cf = 0; cf < 8; ++cf) {
                const int cbyte = (hf * 8 + cf) * 32 + hi * 16;
                af[cf] = *(const bf16x8*)(cbp + rbase + (cbyte ^ (ln31 << 4)));
            }
            #pragma unroll
            for (int cf = 0; cf < 8; ++cf) {
                acc0 = __builtin_amdgcn_mfma_f32_32x32x16_bf16(af[cf], xf[0][hf * 8 + cf].v, acc0, 0, 0, 0);
                acc1 = __builtin_amdgcn_mfma_f32_32x32x16_bf16(af[cf], xf[1][hf * 8 + cf].v, acc1, 0, 0, 0);
            }
        }

        const int kbl = kh * 512 + kc * 32 + hi * 4;
        #pragma unroll
        for (int rg = 0; rg < 16; ++rg) {
            const unsigned kk = (unsigned)(kbl + (rg & 3) + 8 * (rg >> 2));
            const unsigned p0 = (f2u(acc0[rg]) & 0xFFFFFC00u) | kk;
            const unsigned p1 = (f2u(acc1[rg]) & 0xFFFFFC00u) | kk;
            if (rg & 1) { b0b = umin2(b0b, p0); b1b = umin2(b1b, p1); }
            else        { b0a = umin2(b0a, p0); b1a = umin2(b1a, p1); }
        }
        __builtin_amdgcn_s_barrier();
        __builtin_amdgcn_sched_barrier(0);
    }

    // merge chains, then hi halves (disjoint code subsets, same tokens)
    unsigned best0 = umin2(b0a, b0b);
    unsigned best1 = umin2(b1a, b1b);
    best0 = umin2(best0, __shfl_xor(best0, 32));
    best1 = umin2(best1, __shfl_xor(best1, 32));
    if (hi == 0) { kbx[w][ln31] = best0; kbx[w][32 + ln31] = best1; }
    __syncthreads();

    float red = x2s;
    if (kh == 0) {                     // merge K-halves; token = tw0 + tg*64 + lane
        const unsigned key = umin2(kbx[w][lane], kbx[w + 1][lane]);
        keys[tw0 + tg * 64 + lane] = key;
        red += 2.0f * (u2f(key & 0xFFFFFC00u) - 2.0f);
    }
    #pragma unroll
    for (int off = 32; off; off >>= 1) red += __shfl_down(red, off);
    if (lane == 0) wsum[w] = red;
    __syncthreads();
    if (tid == 0) part[blockIdx.x] = wsum[0] + wsum[1] + wsum[2] + wsum[3];
}

// ---------------- scatter v2: 128 tok/block, 8 c-slices, 512B write runs ----------------
__global__ __launch_bounds__(256) void scatter(const float* __restrict__ cb,
                                               const unsigned* __restrict__ keys,
                                               float* __restrict__ out) {
    __shared__ float xs[32][136];      // c-slice x tokens, padded
    __shared__ int kk[128];
    const int tid = threadIdx.x;
    const int n0 = blockIdx.x * 128;
    const int b = n0 >> 12, t0 = n0 & (T_LEN - 1);

    if (tid < 128) kk[tid] = (int)(keys[n0 + tid] & 1023u);
    __syncthreads();

    const int tt = tid & 127, ch = tid >> 7;       // gather: token, c-half (16 c each)
    const int cw = tid >> 5, jj = tid & 31;        // write: c-offset (0..7), t-quad
    const size_t rowbase = (size_t)kk[tt] * DIM + ch * 16;

    for (int sl = 0; sl < 8; ++sl) {
        // issue gather loads before the barrier: L2 latency overlaps prior writes
        const float* row = cb + rowbase + sl * 32;
        const float4 g0 = *reinterpret_cast<const float4*>(row + 0);
        const float4 g1 = *reinterpret_cast<const float4*>(row + 4);
        const float4 g2 = *reinterpret_cast<const float4*>(row + 8);
        const float4 g3 = *reinterpret_cast<const float4*>(row + 12);
        __syncthreads();               // prior slice's xs reads complete
        const int c0 = ch * 16;
        xs[c0 + 0][tt] = g0.x;  xs[c0 + 1][tt] = g0.y;
        xs[c0 + 2][tt] = g0.z;  xs[c0 + 3][tt] = g0.w;
        xs[c0 + 4][tt] = g1.x;  xs[c0 + 5][tt] = g1.y;
        xs[c0 + 6][tt] = g1.z;  xs[c0 + 7][tt] = g1.w;
        xs[c0 + 8][tt] = g2.x;  xs[c0 + 9][tt] = g2.y;
        xs[c0 + 10][tt] = g2.z; xs[c0 + 11][tt] = g2.w;
        xs[c0 + 12][tt] = g3.x; xs[c0 + 13][tt] = g3.y;
        xs[c0 + 14][tt] = g3.z; xs[c0 + 15][tt] = g3.w;
        __syncthreads();
        #pragma unroll
        for (int p = 0; p < 4; ++p) {
            const int c = p * 8 + cw;
            const float4 v = *reinterpret_cast<const float4*>(&xs[c][4 * jj]);
            *reinterpret_cast<float4*>(
                &out[(((size_t)(b * DIM + sl * 32 + c)) << 12) + t0 + 4 * jj]) = v;
        }
    }
}

// ---------------- finalize loss ----------------
__global__ __launch_bounds__(256) void finalize(const float* __restrict__ part,
                                                float* __restrict__ loss_out) {
    double s = (double)part[threadIdx.x] + (double)part[threadIdx.x + 256];
    #pragma unroll
    for (int off = 32; off; off >>= 1) s += __shfl_down(s, off);
    __shared__ double wsum[4];
    const int lane = threadIdx.x & 63, wv = threadIdx.x >> 6;
    if (lane == 0) wsum[wv] = s;
    __syncthreads();
    if (threadIdx.x == 0)
        *loss_out = (float)(2.0 * (wsum[0] + wsum[1] + wsum[2] + wsum[3]) / (double)NELEM);
}

extern "C" void kernel_launch(void* const* d_in, const int* in_sizes, int n_in,
                              void* d_out, int out_size, void* d_ws, size_t ws_size,
                              hipStream_t stream) {
    const float* x  = (const float*)d_in[0];    // [16,256,4096]
    const float* cb = (const float*)d_in[1];    // [1024,256]
    float* out = (float*)d_out;                 // quant (16777216) + loss (1)
    unsigned* ws = (unsigned*)d_ws;
    unsigned* cnh2 = ws;                        // 1024 u32
    float* part = (float*)(ws + 1024);          // 512 f32
    unsigned* keys = ws + 4096;                 // 65536 u32
    unsigned short* cbb = (unsigned short*)out; // 512 KB scratch; dead before scatter

    prep<<<K_CODES / 4, 256, 0, stream>>>(cb, cbb, cnh2);
    argmin_mfma<<<N_TOK / 128, 256, 0, stream>>>(x, cbb, cnh2, keys, part);
    scatter<<<N_TOK / 128, 256, 0, stream>>>(cb, keys, out);
    finalize<<<1, 256, 0, stream>>>(part, out + NELEM);
}

// Round 10
// 62.937 us; speedup vs baseline: 3.2349x; 1.0698x over previous
//
#include <hip/hip_runtime.h>

#define DIM 256
#define T_LEN 4096
#define K_CODES 1024
#define N_TOK 65536
#define NELEM 16777216

// ws layout (32-bit units):
//   [0,1024)        cnh2[k]  packed (bf16_hi | bf16_lo<<16) of 2+0.5|e|^2
//   [1024,1536)     loss partials (512 f32, one per fused block)
//   [4096,135168)   cbb: codebook bf16 row-major (512 KB) -- in ws now, since
//                   d_out is written concurrently by the fused kernel.

typedef __attribute__((ext_vector_type(8))) short bf16x8;
typedef __attribute__((ext_vector_type(16))) float f32x16;

__device__ __forceinline__ unsigned short f2bf(float f) {     // RNE f32->bf16
    unsigned u = __builtin_bit_cast(unsigned, f);
    return (unsigned short)((u + 0x7FFFu + ((u >> 16) & 1u)) >> 16);
}
__device__ __forceinline__ float bf2f(unsigned short h) {
    return __builtin_bit_cast(float, (unsigned)h << 16);
}
__device__ __forceinline__ unsigned f2u(float f) { return __builtin_bit_cast(unsigned, f); }
__device__ __forceinline__ float u2f(unsigned u) { return __builtin_bit_cast(float, u); }
__device__ __forceinline__ unsigned umin2(unsigned a, unsigned b) { return a < b ? a : b; }

union FragU { bf16x8 v; unsigned short u[8]; unsigned w[4]; };

#define GLLOAD(gsrc, lbase)                                                              \
    __builtin_amdgcn_global_load_lds(                                                    \
        (const __attribute__((address_space(1))) unsigned int*)(gsrc),                   \
        (__attribute__((address_space(3))) unsigned int*)(lbase), 16, 0, 0)

// cvt two f32 -> packed bf16 pair, NEGATED (folds -x for the cn-fold trick), RNE.
__device__ __forceinline__ unsigned cvtpk_neg(float a, float b) {
    unsigned r;
    asm("v_cvt_pk_bf16_f32 %0, -%1, -%2" : "=v"(r) : "v"(a), "v"(b));
    return r;
}

// ---------------- prep: cb->bf16 (row-major, into ws), cnh2 split pair ----------------
__global__ __launch_bounds__(256) void prep(const float* __restrict__ cb,
                                            unsigned short* __restrict__ cbb,
                                            unsigned* __restrict__ cnh2) {
    const int k = blockIdx.x * 4 + (threadIdx.x >> 6);
    const int lane = threadIdx.x & 63;
    float4 v = *reinterpret_cast<const float4*>(cb + (size_t)k * DIM + lane * 4);
    float s = v.x * v.x + v.y * v.y + v.z * v.z + v.w * v.w;
    #pragma unroll
    for (int off = 32; off; off >>= 1) s += __shfl_down(s, off);
    if (lane == 0) {
        float cn = 2.0f + 0.5f * s;
        unsigned short chi = f2bf(cn);
        unsigned short clo = f2bf(cn - bf2f(chi));
        cnh2[k] = (unsigned)chi | ((unsigned)clo << 16);
    }
    ushort4 o;
    o.x = f2bf(v.x); o.y = f2bf(v.y); o.z = f2bf(v.z); o.w = f2bf(v.w);
    *reinterpret_cast<ushort4*>(cbb + (size_t)k * DIM + lane * 4) = o;
}

// ---------------- fused: argmin sweep (r9-proven) + scatter + loss ----------------
// 512 blocks x 4 waves. Wave pair (tg, kh): tg = token group (64 tok), kh = K-half.
// After the kh-merge, the block scatters its own 128 tokens (gather fp32 rows from
// L2, transpose through the freed cbuf, coalesced float4 writes) -- no separate
// kernel, no keys round-trip; out-writes overlap other blocks' sweeps.
__global__ __launch_bounds__(256, 2) void vq_fused(const float* __restrict__ x,
                                                   const unsigned short* __restrict__ cbb,
                                                   const unsigned* __restrict__ cnh2,
                                                   const float* __restrict__ cbf,
                                                   float* __restrict__ out,
                                                   float* __restrict__ part) {
    __shared__ __align__(16) unsigned short cbuf[2][16 * 1024];  // 2 x 32 KB
    __shared__ unsigned cnl[1024];                               // 4 KB
    __shared__ unsigned kbx[4][64];                              // 1 KB key exchange
    __shared__ int kkl[128];                                     // merged codes
    __shared__ float wsum[4];
    const int tid = threadIdx.x;
    const int w = tid >> 6, lane = tid & 63, hi = lane >> 5, ln31 = lane & 31;
    const int tg = w >> 1;                    // token group (0,1): 64 tokens each
    const int kh = w & 1;                     // codebook half (0,1)
    const int tw0 = blockIdx.x * 128;
    const int b = tw0 >> 12, tb = tw0 & (T_LEN - 1);

    cnl[tid] = cnh2[tid];
    cnl[tid + 256] = cnh2[tid + 256];
    cnl[tid + 512] = cnh2[tid + 512];
    cnl[tid + 768] = cnh2[tid + 768];

    // ---- x ingest: [128 t][128 c] bf16 tile per c-half, half h -> cbuf[h] ----
    const int tqi = tid & 31, cqi = tid >> 5;
    const float* xb = x + (size_t)b * DIM * T_LEN + tb + 4 * tqi;
    const int wswz = (tqi & 7) << 4;
    float x2s = 0.0f;

    #pragma unroll
    for (int h = 0; h < 2; ++h) {
        char* lds = (char*)&cbuf[h][0];
        #pragma unroll
        for (int ii = 0; ii < 4; ++ii) {
            const int cl = (ii * 8 + cqi) * 4;                  // c within half
            const float* p = xb + (size_t)(h * 128 + cl) * T_LEN;
            const float4 P0 = *reinterpret_cast<const float4*>(p);
            const float4 P1 = *reinterpret_cast<const float4*>(p + T_LEN);
            const float4 P2 = *reinterpret_cast<const float4*>(p + 2 * T_LEN);
            const float4 P3 = *reinterpret_cast<const float4*>(p + 3 * T_LEN);
            x2s = fmaf(P0.x, P0.x, fmaf(P0.y, P0.y, fmaf(P0.z, P0.z, fmaf(P0.w, P0.w, x2s))));
            x2s = fmaf(P1.x, P1.x, fmaf(P1.y, P1.y, fmaf(P1.z, P1.z, fmaf(P1.w, P1.w, x2s))));
            x2s = fmaf(P2.x, P2.x, fmaf(P2.y, P2.y, fmaf(P2.z, P2.z, fmaf(P2.w, P2.w, x2s))));
            x2s = fmaf(P3.x, P3.x, fmaf(P3.y, P3.y, fmaf(P3.z, P3.z, fmaf(P3.w, P3.w, x2s))));
            const unsigned l0 = cvtpk_neg(P0.x, P0.y), h0 = cvtpk_neg(P0.z, P0.w);
            const unsigned l1 = cvtpk_neg(P1.x, P1.y), h1 = cvtpk_neg(P1.z, P1.w);
            const unsigned l2 = cvtpk_neg(P2.x, P2.y), h2 = cvtpk_neg(P2.z, P2.w);
            const unsigned l3 = cvtpk_neg(P3.x, P3.y), h3 = cvtpk_neg(P3.z, P3.w);
            const unsigned q0a = __builtin_amdgcn_perm(l1, l0, 0x05040100u);
            const unsigned q0b = __builtin_amdgcn_perm(h1, h0, 0x05040100u);
            const unsigned q1a = __builtin_amdgcn_perm(l1, l0, 0x07060302u);
            const unsigned q1b = __builtin_amdgcn_perm(h1, h0, 0x07060302u);
            const unsigned q2a = __builtin_amdgcn_perm(l3, l2, 0x05040100u);
            const unsigned q2b = __builtin_amdgcn_perm(h3, h2, 0x05040100u);
            const unsigned q3a = __builtin_amdgcn_perm(l3, l2, 0x07060302u);
            const unsigned q3b = __builtin_amdgcn_perm(h3, h2, 0x07060302u);
            const int t4 = 4 * tqi, cb2 = cl * 2;
            uint2 u;
            u.x = q0a; u.y = q0b;
            *reinterpret_cast<uint2*>(lds + ((((t4 + 0) << 8) + cb2) ^ wswz)) = u;
            u.x = q1a; u.y = q1b;
            *reinterpret_cast<uint2*>(lds + ((((t4 + 1) << 8) + cb2) ^ wswz)) = u;
            u.x = q2a; u.y = q2b;
            *reinterpret_cast<uint2*>(lds + ((((t4 + 2) << 8) + cb2) ^ wswz)) = u;
            u.x = q3a; u.y = q3b;
            *reinterpret_cast<uint2*>(lds + ((((t4 + 3) << 8) + cb2) ^ wswz)) = u;
        }
    }
    __syncthreads();
    FragU xf[2][16];                    // NEGATED bf16 frags: this pair's 64 tokens
    {
        #pragma unroll
        for (int g = 0; g < 2; ++g) {
            const int tp = tg * 64 + g * 32 + ln31;
            const int rswz = ((tp >> 2) & 7) << 4;
            #pragma unroll
            for (int h = 0; h < 2; ++h) {
                const char* lds = (const char*)&cbuf[h][0];
                #pragma unroll
                for (int cf = 0; cf < 8; ++cf) {
                    int ad = (tp << 8) + cf * 32 + hi * 16;
                    xf[g][h * 8 + cf].v = *reinterpret_cast<const bf16x8*>(lds + (ad ^ rswz));
                }
            }
        }
    }
    __syncthreads();

    // ---- staging: both halves' chunk kc (2 x 16 KB) into buf ----
    auto stage = [&](int kc, int buf) {
        char* lb = (char*)&cbuf[buf][0];
        const char* g0 = (const char*)cbb + kc * 16384;            // codes kc*32..
        const char* g1 = (const char*)cbb + 262144 + kc * 16384;   // codes 512+kc*32..
        #pragma unroll
        for (int j = 0; j < 8; ++j) {
            const int jj = j & 3;
            const int o = jj * 4096 + w * 1024 + lane * 16;
            const int so = o ^ (((o >> 9) & 31) << 4);
            GLLOAD((j < 4 ? g0 : g1) + so, lb + (j >> 2) * 16384 + jj * 4096 + w * 1024);
        }
    };
    stage(0, 0);

    FragU onef;                                   // B-const: k=0,1 -> 1.0
    #pragma unroll
    for (int i = 0; i < 8; ++i) onef.u[i] = (hi == 0 && i < 2) ? 0x3F80 : 0;

    unsigned b0a = 0xFFFFFFFFu, b0b = 0xFFFFFFFFu;   // acc0 chains
    unsigned b1a = 0xFFFFFFFFu, b1b = 0xFFFFFFFFu;   // acc1 chains

    for (int kc = 0; kc < 16; ++kc) {
        const int cur = kc & 1;
        if (kc < 15) {
            stage(kc + 1, cur ^ 1);
            asm volatile("s_waitcnt vmcnt(8)" ::: "memory");   // chunk kc landed
        } else {
            asm volatile("s_waitcnt vmcnt(0)" ::: "memory");
        }
        __builtin_amdgcn_s_barrier();
        __builtin_amdgcn_sched_barrier(0);

        const char* cbp = (const char*)&cbuf[cur][0] + kh * 16384;
        const unsigned d = cnl[kh * 512 + kc * 32 + ln31];
        FragU cfr;
        cfr.u[0] = hi ? (unsigned short)0 : (unsigned short)(d & 0xFFFFu);
        cfr.u[1] = hi ? (unsigned short)0 : (unsigned short)(d >> 16);
        #pragma unroll
        for (int i = 2; i < 8; ++i) cfr.u[i] = 0;

        f32x16 acc0, acc1;
        #pragma unroll
        for (int i = 0; i < 16; ++i) { acc0[i] = 0.0f; acc1[i] = 0.0f; }
        acc0 = __builtin_amdgcn_mfma_f32_32x32x16_bf16(cfr.v, onef.v, acc0, 0, 0, 0);
        acc1 = __builtin_amdgcn_mfma_f32_32x32x16_bf16(cfr.v, onef.v, acc1, 0, 0, 0);

        const int rbase = ln31 * 512;
        #pragma unroll
        for (int hf = 0; hf < 2; ++hf) {            // two 8-frag halves: af reuse
            bf16x8 af[8];
            #pragma unroll
            for (int cf = 0; cf < 8; ++cf) {
                const int cbyte = (hf * 8 + cf) * 32 + hi * 16;
                af[cf] = *(const bf16x8*)(cbp + rbase + (cbyte ^ (ln31 << 4)));
            }
            #pragma unroll
            for (int cf = 0; cf < 8; ++cf) {
                acc0 = __builtin_amdgcn_mfma_f32_32x32x16_bf16(af[cf], xf[0][hf * 8 + cf].v, acc0, 0, 0, 0);
                acc1 = __builtin_amdgcn_mfma_f32_32x32x16_bf16(af[cf], xf[1][hf * 8 + cf].v, acc1, 0, 0, 0);
            }
        }

        const int kbl = kh * 512 + kc * 32 + hi * 4;
        #pragma unroll
        for (int rg = 0; rg < 16; ++rg) {
            const unsigned kk = (unsigned)(kbl + (rg & 3) + 8 * (rg >> 2));
            const unsigned p0 = (f2u(acc0[rg]) & 0xFFFFFC00u) | kk;
            const unsigned p1 = (f2u(acc1[rg]) & 0xFFFFFC00u) | kk;
            if (rg & 1) { b0b = umin2(b0b, p0); b1b = umin2(b1b, p1); }
            else        { b0a = umin2(b0a, p0); b1a = umin2(b1a, p1); }
        }
        __builtin_amdgcn_s_barrier();
        __builtin_amdgcn_sched_barrier(0);
    }

    // merge chains, then hi halves (disjoint code subsets, same tokens)
    unsigned best0 = umin2(b0a, b0b);
    unsigned best1 = umin2(b1a, b1b);
    best0 = umin2(best0, __shfl_xor(best0, 32));
    best1 = umin2(best1, __shfl_xor(best1, 32));
    if (hi == 0) { kbx[w][ln31] = best0; kbx[w][32 + ln31] = best1; }
    __syncthreads();

    float red = x2s;
    if (kh == 0) {                     // merge K-halves; token = tw0 + tg*64 + lane
        const unsigned key = umin2(kbx[w][lane], kbx[w + 1][lane]);
        kkl[tg * 64 + lane] = (int)(key & 1023u);
        red += 2.0f * (u2f(key & 0xFFFFFC00u) - 2.0f);
    }
    #pragma unroll
    for (int off = 32; off; off >>= 1) red += __shfl_down(red, off);
    if (lane == 0) wsum[w] = red;
    __syncthreads();
    if (tid == 0) part[blockIdx.x] = wsum[0] + wsum[1] + wsum[2] + wsum[3];

    // ---- fused scatter: gather fp32 rows (L2) -> LDS transpose -> coalesced out ----
    float* fs = (float*)&cbuf[0][0];               // [64 c][136 t] f32 = 34.8 KB
    const int tt = tid & 127, ch = tid >> 7;       // gather: token, c-half (32 c)
    const size_t rowb = (size_t)kkl[tt] * DIM;
    #pragma unroll 1
    for (int sl = 0; sl < 4; ++sl) {
        float4 g[8];
        #pragma unroll
        for (int i = 0; i < 8; ++i)
            g[i] = *reinterpret_cast<const float4*>(cbf + rowb + sl * 64 + ch * 32 + 4 * i);
        __syncthreads();                           // prev slice reads done
        #pragma unroll
        for (int i = 0; i < 8; ++i) {
            const int c0 = ch * 32 + 4 * i;
            fs[(c0 + 0) * 136 + tt] = g[i].x;
            fs[(c0 + 1) * 136 + tt] = g[i].y;
            fs[(c0 + 2) * 136 + tt] = g[i].z;
            fs[(c0 + 3) * 136 + tt] = g[i].w;
        }
        __syncthreads();
        #pragma unroll
        for (int p = 0; p < 8; ++p) {
            const int c = p * 8 + (tid >> 5), th = tid & 31;
            const float4 v = *reinterpret_cast<const float4*>(fs + c * 136 + 4 * th);
            *reinterpret_cast<float4*>(
                out + (((size_t)(b * DIM + sl * 64 + c)) << 12) + tb + 4 * th) = v;
        }
    }
}

// ---------------- finalize loss ----------------
__global__ __launch_bounds__(256) void finalize(const float* __restrict__ part,
                                                float* __restrict__ loss_out) {
    double s = (double)part[threadIdx.x] + (double)part[threadIdx.x + 256];
    #pragma unroll
    for (int off = 32; off; off >>= 1) s += __shfl_down(s, off);
    __shared__ double wsum[4];
    const int lane = threadIdx.x & 63, wv = threadIdx.x >> 6;
    if (lane == 0) wsum[wv] = s;
    __syncthreads();
    if (threadIdx.x == 0)
        *loss_out = (float)(2.0 * (wsum[0] + wsum[1] + wsum[2] + wsum[3]) / (double)NELEM);
}

extern "C" void kernel_launch(void* const* d_in, const int* in_sizes, int n_in,
                              void* d_out, int out_size, void* d_ws, size_t ws_size,
                              hipStream_t stream) {
    const float* x  = (const float*)d_in[0];    // [16,256,4096]
    const float* cb = (const float*)d_in[1];    // [1024,256]
    float* out = (float*)d_out;                 // quant (16777216) + loss (1)
    unsigned* ws = (unsigned*)d_ws;
    unsigned* cnh2 = ws;                        // 1024 u32
    float* part = (float*)(ws + 1024);          // 512 f32
    unsigned short* cbb = (unsigned short*)(ws + 4096);  // 512 KB bf16 codebook

    prep<<<K_CODES / 4, 256, 0, stream>>>(cb, cbb, cnh2);
    vq_fused<<<N_TOK / 128, 256, 0, stream>>>(x, cbb, cnh2, cb, out, part);
    finalize<<<1, 256, 0, stream>>>(part, out + NELEM);
}